// Round 1
// 6691.534 us; speedup vs baseline: 1.1389x; 1.1389x over previous
//
#include <hip/hip_runtime.h>
#include <cstdint>
#include <cstddef>

typedef __attribute__((ext_vector_type(8))) short short8;
typedef __attribute__((ext_vector_type(4))) float floatx4;
typedef unsigned short u16;

#define NSTEP 256

__device__ __forceinline__ unsigned f2b_rne(float x) {
  unsigned u = __builtin_bit_cast(unsigned, x);
  return (u + 0x7fffu + ((u >> 16) & 1u)) >> 16;
}
__device__ __forceinline__ float b2f(u16 b) {
  unsigned u = ((unsigned)b) << 16;
  return __builtin_bit_cast(float, u);
}
__device__ __forceinline__ float sigf(float x) {
  x = fminf(fmaxf(x, -30.f), 30.f);
  return __builtin_amdgcn_rcpf(1.f + __expf(-x));
}
__device__ __forceinline__ float tanhf_fast(float x) {
  x = fminf(fmaxf(x, -15.f), 15.f);
  float e = __expf(2.f * x);
  return (e - 1.f) * __builtin_amdgcn_rcpf(e + 1.f);
}

// ---------------- init: zero h rows t=0 and barrier counters ----------------
__global__ void init_kernel(u16* h0, u16* h1, unsigned* ctr) {
  int i = blockIdx.x * blockDim.x + threadIdx.x;
  if (i < 65536) { h0[i] = 0; h1[i] = 0; }
  if (i < 128) ctr[i] = 0;
}

// ---------------- fp32 -> bf16 cast (vectorized x4) ----------------
__global__ void cast_kernel(const float* __restrict__ in, u16* __restrict__ out, int n4) {
  int i = blockIdx.x * blockDim.x + threadIdx.x;
  int stride = gridDim.x * blockDim.x;
  for (; i < n4; i += stride) {
    float4 v = ((const float4*)in)[i];
    unsigned lo = f2b_rne(v.x) | (f2b_rne(v.y) << 16);
    unsigned hi = f2b_rne(v.z) | (f2b_rne(v.w) << 16);
    ((uint2*)out)[i] = make_uint2(lo, hi);
  }
}

// ---------------- big NT GEMM: C[16384][4096] bf16 = A[16384][1024] @ B[4096][1024]^T
// AL==0: A plain row-major [m][k]. (AL==1 blocked variant retained but unused.)
template<int AL>
__global__ __launch_bounds__(256) void gemm_nt(
    const u16* __restrict__ A, const u16* __restrict__ B, u16* __restrict__ C) {
  __shared__ u16 As[128 * 32];
  __shared__ u16 Bs[128 * 32];
  const int bid = blockIdx.x;
  const int m_blk = (bid >> 5) << 7;
  const int n_blk = (bid & 31) << 7;
  const int tid = threadIdx.x;
  const int wv = tid >> 6, lane = tid & 63;
  const int q = lane >> 4, n16 = lane & 15;
  const int m0w = (wv >> 1) << 6, n0w = (wv & 1) << 6;

  const floatx4 vzero = {0.f, 0.f, 0.f, 0.f};
  floatx4 acc[4][4];
#pragma unroll
  for (int mt = 0; mt < 4; ++mt)
#pragma unroll
    for (int nt = 0; nt < 4; ++nt) acc[mt][nt] = vzero;

  for (int k0 = 0; k0 < 1024; k0 += 32) {
#pragma unroll
    for (int i = 0; i < 2; ++i) {
      int s = i * 256 + tid;           // slot 0..511
      int r = s >> 2, kk = (s & 3) << 3;
      int m = m_blk + r, k = k0 + kk;
      size_t a_off;
      if (AL == 0) a_off = (size_t)m * 1024 + k;
      else a_off = (size_t)(m >> 6) * 65536 + (size_t)(k >> 4) * 1024 + (size_t)(m & 63) * 16 + (k & 15);
      size_t b_off = (size_t)(n_blk + r) * 1024 + k;
      __builtin_amdgcn_global_load_lds(
          (const __attribute__((address_space(1))) unsigned int*)(A + a_off),
          (__attribute__((address_space(3))) unsigned int*)(As + (size_t)(i * 256 + wv * 64) * 8),
          16, 0, 0);
      __builtin_amdgcn_global_load_lds(
          (const __attribute__((address_space(1))) unsigned int*)(B + b_off),
          (__attribute__((address_space(3))) unsigned int*)(Bs + (size_t)(i * 256 + wv * 64) * 8),
          16, 0, 0);
    }
    __syncthreads();
    short8 af[4], bf[4];
#pragma unroll
    for (int mt = 0; mt < 4; ++mt)
      af[mt] = *(const short8*)(As + (m0w + mt * 16 + n16) * 32 + q * 8);
#pragma unroll
    for (int nt = 0; nt < 4; ++nt)
      bf[nt] = *(const short8*)(Bs + (n0w + nt * 16 + n16) * 32 + q * 8);
#pragma unroll
    for (int mt = 0; mt < 4; ++mt)
#pragma unroll
      for (int nt = 0; nt < 4; ++nt)
        acc[mt][nt] = __builtin_amdgcn_mfma_f32_16x16x32_bf16(af[mt], bf[nt], acc[mt][nt], 0, 0, 0);
    __syncthreads();
  }
#pragma unroll
  for (int mt = 0; mt < 4; ++mt)
#pragma unroll
    for (int nt = 0; nt < 4; ++nt)
#pragma unroll
      for (int r = 0; r < 4; ++r) {
        int m = m_blk + m0w + mt * 16 + q * 4 + r;
        int n = n_blk + n0w + nt * 16 + n16;
        C[(size_t)m * 4096 + n] = (u16)f2b_rne(acc[mt][nt][r]);
      }
}

// ---------------- spin helper (relaxed agent-scope polls, fences by caller) ---
__device__ __forceinline__ void spin_until(unsigned* c, unsigned target) {
  int spins = 0;
  while (__hip_atomic_load(c, __ATOMIC_RELAXED, __HIP_MEMORY_SCOPE_AGENT) < target) {
    __builtin_amdgcn_s_sleep(2);
    if (++spins > (1 << 17)) break;  // liveness guard
  }
}

// ---------------- fused persistent 2-layer LSTM recurrence ----------------
// 128 WGs x 256 threads. blockIdx<64 -> layer 0, else layer 1. WG owns 16
// hidden units (all 4 gates). Layer 0 runs the EXACT previous protocol on
// ctr0 (release wbl2 -> relaxed add -> relaxed spin -> acquire inv). Layer 1
// software-pipelines one step behind: at its step t it reads h0 row t+1
// (gated on ctr0 >= 64*(t+1)) and its own row t (gated by its peer barrier
// on ctr1). Layer 0 never reads layer-1 data, so it free-runs; the two
// recurrences overlap in wall time. Layer 1 computes x@Wx1^T in-loop (Wx1
// fragments in registers, K=2048 total split 512/wave), eliminating the
// second big GEMM dispatch.
__global__ __launch_bounds__(256, 1) void lstm_fused(
    const u16* __restrict__ Wh0b,   // [4096][1024] bf16
    const u16* __restrict__ Wx1b,   // [4096][1024] bf16
    const u16* __restrict__ Wh1b,   // [4096][1024] bf16
    const u16* __restrict__ G,      // [16384][4096] bf16 (x@Wx0^T, no bias)
    const float* __restrict__ bias, // [2][4096]
    u16* H0buf,                     // blocked [257 rows], read+write (no restrict!)
    u16* H1buf,
    float* __restrict__ outp,       // [256*64*1024] fp32 (layer-1 output)
    float* __restrict__ hf,         // [2*64*1024] fp32
    float* __restrict__ cf,         // [2*64*1024] fp32
    unsigned* ctr) {
  __shared__ float red[4][12][256];
  const int tid = threadIdx.x;
  const int wv = tid >> 6;
  const int lane = tid & 63;
  const int q = lane >> 4;
  const int n16 = lane & 15;
  const int layer = blockIdx.x >> 6;
  const int jb = blockIdx.x & 63;
  const int j0 = jb << 4;
  const int jg = j0 + n16;
  const int kq0 = wv << 8;
  unsigned* ctr0 = ctr;
  unsigned* ctr1 = ctr + 64;
  const floatx4 vzero = {0.f, 0.f, 0.f, 0.f};

  float bs[4];
#pragma unroll
  for (int g = 0; g < 4; ++g) bs[g] = bias[layer * 4096 + g * 1024 + jg];
  float cst[4] = {0.f, 0.f, 0.f, 0.f};

  if (layer == 0) {
    // ---------------- layer 0: identical to proven single-layer kernel ------
    short8 wf[4][8];
#pragma unroll
    for (int g = 0; g < 4; ++g)
#pragma unroll
      for (int c = 0; c < 8; ++c)
        wf[g][c] = *(const short8*)(Wh0b + (size_t)(g * 1024 + jg) * 1024 + kq0 + c * 32 + q * 8);

    // preload G fragment for t=0
    float gf[4][4];
#pragma unroll
    for (int g = 0; g < 4; ++g)
#pragma unroll
      for (int r = 0; r < 4; ++r)
        gf[g][r] = b2f(G[(size_t)(wv * 16 + q * 4 + r) * 4096 + g * 1024 + jg]);

    for (int t = 0; t < NSTEP; ++t) {
      const u16* hrow = H0buf + (size_t)t * 65536;

      floatx4 acc[4][4];
#pragma unroll
      for (int m = 0; m < 4; ++m)
#pragma unroll
        for (int g = 0; g < 4; ++g) acc[m][g] = vzero;

#pragma unroll
      for (int c = 0; c < 8; ++c) {
        int k = kq0 + c * 32 + q * 8;
        const u16* hbase = hrow + (size_t)(k >> 4) * 1024 + (k & 15);
        short8 a[4];
#pragma unroll
        for (int m = 0; m < 4; ++m)
          a[m] = *(const short8*)(hbase + (m * 16 + n16) * 16);
#pragma unroll
        for (int m = 0; m < 4; ++m)
#pragma unroll
          for (int g = 0; g < 4; ++g)
            acc[m][g] = __builtin_amdgcn_mfma_f32_16x16x32_bf16(a[m], wf[g][c], acc[m][g], 0, 0, 0);
      }

      // cross-wave K reduction via LDS
#pragma unroll
      for (int m = 0; m < 4; ++m) {
        if (m == wv) continue;
        int slot = (m - (m > wv ? 1 : 0)) * 4;
#pragma unroll
        for (int g = 0; g < 4; ++g)
          *(floatx4*)&red[wv][slot + g][lane * 4] = acc[m][g];
      }
      __syncthreads();
      floatx4 tot[4];
#pragma unroll
      for (int g = 0; g < 4; ++g) tot[g] = acc[wv][g];
#pragma unroll
      for (int w2 = 0; w2 < 4; ++w2) {
        if (w2 == wv) continue;
        int slot = (wv - (wv > w2 ? 1 : 0)) * 4;
#pragma unroll
        for (int g = 0; g < 4; ++g)
          tot[g] += *(const floatx4*)&red[w2][slot + g][lane * 4];
      }

      u16* hnext = H0buf + (size_t)(t + 1) * 65536 + (size_t)jb * 1024;
#pragma unroll
      for (int r = 0; r < 4; ++r) {
        float pi = tot[0][r] + gf[0][r] + bs[0];
        float pf = tot[1][r] + gf[1][r] + bs[1];
        float po = tot[2][r] + gf[2][r] + bs[2];
        float pc = tot[3][r] + gf[3][r] + bs[3];
        float cn = sigf(pf) * cst[r] + sigf(pi) * tanhf_fast(pc);
        float h = sigf(po) * tanhf_fast(cn);
        cst[r] = cn;
        int brow = wv * 16 + q * 4 + r;
        hnext[brow * 16 + n16] = (u16)f2b_rne(h);
        if (t == NSTEP - 1) {
          hf[brow * 1024 + jg] = h;
          cf[brow * 1024 + jg] = cn;
        }
      }

      // prefetch next-step G into registers before the barrier
      if (t + 1 < NSTEP) {
#pragma unroll
        for (int g = 0; g < 4; ++g)
#pragma unroll
          for (int r = 0; r < 4; ++r)
            gf[g][r] = b2f(G[(size_t)((t + 1) * 64 + wv * 16 + q * 4 + r) * 4096 + g * 1024 + jg]);
      }

      __syncthreads();
      if (tid == 0) {
        __builtin_amdgcn_fence(__ATOMIC_RELEASE, "agent");
        __hip_atomic_fetch_add(ctr0, 1u, __ATOMIC_RELAXED, __HIP_MEMORY_SCOPE_AGENT);
        if (t + 1 < NSTEP) {
          spin_until(ctr0, 64u * (unsigned)(t + 1));
          __builtin_amdgcn_fence(__ATOMIC_ACQUIRE, "agent");
        }
      }
      __syncthreads();
    }
  } else {
    // ---------------- layer 1: one step behind, K=2048 (Wx1 cat Wh1) --------
    short8 wfx[4][8], wfh[4][8];
#pragma unroll
    for (int g = 0; g < 4; ++g)
#pragma unroll
      for (int c = 0; c < 8; ++c) {
        wfx[g][c] = *(const short8*)(Wx1b + (size_t)(g * 1024 + jg) * 1024 + kq0 + c * 32 + q * 8);
        wfh[g][c] = *(const short8*)(Wh1b + (size_t)(g * 1024 + jg) * 1024 + kq0 + c * 32 + q * 8);
      }

    // initial gate: h0 row 1 must exist
    if (tid == 0) {
      spin_until(ctr0, 64u);
      __builtin_amdgcn_fence(__ATOMIC_ACQUIRE, "agent");
    }
    __syncthreads();

    for (int t = 0; t < NSTEP; ++t) {
      const u16* xrow = H0buf + (size_t)(t + 1) * 65536;  // layer-0 output at step t
      const u16* hrow = H1buf + (size_t)t * 65536;        // own state

      floatx4 acc[4][4];
#pragma unroll
      for (int m = 0; m < 4; ++m)
#pragma unroll
        for (int g = 0; g < 4; ++g) acc[m][g] = vzero;

      // x @ Wx1^T (this wave's K-quarter of the 1024 x-dims)
#pragma unroll
      for (int c = 0; c < 8; ++c) {
        int k = kq0 + c * 32 + q * 8;
        const u16* xbase = xrow + (size_t)(k >> 4) * 1024 + (k & 15);
        short8 a[4];
#pragma unroll
        for (int m = 0; m < 4; ++m)
          a[m] = *(const short8*)(xbase + (m * 16 + n16) * 16);
#pragma unroll
        for (int m = 0; m < 4; ++m)
#pragma unroll
          for (int g = 0; g < 4; ++g)
            acc[m][g] = __builtin_amdgcn_mfma_f32_16x16x32_bf16(a[m], wfx[g][c], acc[m][g], 0, 0, 0);
      }
      // h @ Wh1^T (this wave's K-quarter of the 1024 h-dims)
#pragma unroll
      for (int c = 0; c < 8; ++c) {
        int k = kq0 + c * 32 + q * 8;
        const u16* hbase = hrow + (size_t)(k >> 4) * 1024 + (k & 15);
        short8 a[4];
#pragma unroll
        for (int m = 0; m < 4; ++m)
          a[m] = *(const short8*)(hbase + (m * 16 + n16) * 16);
#pragma unroll
        for (int m = 0; m < 4; ++m)
#pragma unroll
          for (int g = 0; g < 4; ++g)
            acc[m][g] = __builtin_amdgcn_mfma_f32_16x16x32_bf16(a[m], wfh[g][c], acc[m][g], 0, 0, 0);
      }

      // cross-wave K reduction via LDS
#pragma unroll
      for (int m = 0; m < 4; ++m) {
        if (m == wv) continue;
        int slot = (m - (m > wv ? 1 : 0)) * 4;
#pragma unroll
        for (int g = 0; g < 4; ++g)
          *(floatx4*)&red[wv][slot + g][lane * 4] = acc[m][g];
      }
      __syncthreads();
      floatx4 tot[4];
#pragma unroll
      for (int g = 0; g < 4; ++g) tot[g] = acc[wv][g];
#pragma unroll
      for (int w2 = 0; w2 < 4; ++w2) {
        if (w2 == wv) continue;
        int slot = (wv - (wv > w2 ? 1 : 0)) * 4;
#pragma unroll
        for (int g = 0; g < 4; ++g)
          tot[g] += *(const floatx4*)&red[w2][slot + g][lane * 4];
      }

      u16* hnext = H1buf + (size_t)(t + 1) * 65536 + (size_t)jb * 1024;
#pragma unroll
      for (int r = 0; r < 4; ++r) {
        float pi = tot[0][r] + bs[0];
        float pf = tot[1][r] + bs[1];
        float po = tot[2][r] + bs[2];
        float pc = tot[3][r] + bs[3];
        float cn = sigf(pf) * cst[r] + sigf(pi) * tanhf_fast(pc);
        float h = sigf(po) * tanhf_fast(cn);
        cst[r] = cn;
        int brow = wv * 16 + q * 4 + r;
        hnext[brow * 16 + n16] = (u16)f2b_rne(h);
        outp[((size_t)t * 64 + brow) * 1024 + jg] = h;
        if (t == NSTEP - 1) {
          hf[65536 + brow * 1024 + jg] = h;
          cf[65536 + brow * 1024 + jg] = cn;
        }
      }

      __syncthreads();
      if (tid == 0) {
        __builtin_amdgcn_fence(__ATOMIC_RELEASE, "agent");
        __hip_atomic_fetch_add(ctr1, 1u, __ATOMIC_RELAXED, __HIP_MEMORY_SCOPE_AGENT);
        if (t + 1 < NSTEP) {
          spin_until(ctr1, 64u * (unsigned)(t + 1));   // own peers: h1 row t+1 done
          spin_until(ctr0, 64u * (unsigned)(t + 2));   // layer 0: h0 row t+2 done
          __builtin_amdgcn_fence(__ATOMIC_ACQUIRE, "agent");
        }
      }
      __syncthreads();
    }
  }
}

// ---------------- launch ----------------
extern "C" void kernel_launch(void* const* d_in, const int* in_sizes, int n_in,
                              void* d_out, int out_size, void* d_ws, size_t ws_size,
                              hipStream_t stream) {
  const float* X  = (const float*)d_in[0];   // [256][64][1024]
  const float* Wx = (const float*)d_in[1];   // [2][4096][1024]
  const float* Wh = (const float*)d_in[2];   // [2][4096][1024]
  const float* b  = (const float*)d_in[3];   // [2][4096]
  float* out = (float*)d_out;

  char* ws = (char*)d_ws;
  u16* Xbf  = (u16*)(ws);                         // 33,554,432 B
  u16* Wxbf = (u16*)(ws + 33554432);              // 16,777,216 B
  u16* Whbf = (u16*)(ws + 50331648);              // 16,777,216 B
  u16* H0   = (u16*)(ws + 67108864);              // 33,685,504 B (257*65536*2)
  u16* H1   = (u16*)(ws + 100794368);             // 33,685,504 B
  u16* G    = (u16*)(ws + 134479872);             // 134,217,728 B
  unsigned* ctr = (unsigned*)(ws + 268697600);    // 256 B

  float* out_seq = out;                // 16,777,216 floats
  float* Hf = out + 16777216;          // 131,072 floats
  float* Cf = out + 16777216 + 131072; // 131,072 floats

  init_kernel<<<256, 256, 0, stream>>>(H0, H1, ctr);
  cast_kernel<<<2048, 256, 0, stream>>>(X, Xbf, 16777216 / 4);
  cast_kernel<<<2048, 256, 0, stream>>>(Wx, Wxbf, 8388608 / 4);
  cast_kernel<<<2048, 256, 0, stream>>>(Wh, Whbf, 8388608 / 4);

  // layer-0 input GEMM: G = X @ Wx0^T (layer-1's input GEMM is fused in-loop)
  gemm_nt<0><<<4096, 256, 0, stream>>>(Xbf, Wxbf, G);

  // fused pipelined 2-layer recurrence
  lstm_fused<<<128, 256, 0, stream>>>(Whbf, Wxbf + 4194304, Whbf + 4194304, G, b,
                                      H0, H1, out_seq, Hf, Cf, ctr);
}

// Round 2
// 5903.846 us; speedup vs baseline: 1.2908x; 1.1334x over previous
//
#include <hip/hip_runtime.h>
#include <cstdint>
#include <cstddef>

typedef __attribute__((ext_vector_type(8))) short short8;
typedef __attribute__((ext_vector_type(4))) float floatx4;
typedef unsigned short u16;

#define NSTEP 256

__device__ __forceinline__ unsigned f2b_rne(float x) {
  unsigned u = __builtin_bit_cast(unsigned, x);
  return (u + 0x7fffu + ((u >> 16) & 1u)) >> 16;
}
__device__ __forceinline__ float b2f(u16 b) {
  unsigned u = ((unsigned)b) << 16;
  return __builtin_bit_cast(float, u);
}
__device__ __forceinline__ float sigf(float x) {
  x = fminf(fmaxf(x, -30.f), 30.f);
  return __builtin_amdgcn_rcpf(1.f + __expf(-x));
}
__device__ __forceinline__ float tanhf_fast(float x) {
  x = fminf(fmaxf(x, -15.f), 15.f);
  float e = __expf(2.f * x);
  return (e - 1.f) * __builtin_amdgcn_rcpf(e + 1.f);
}

// agent-scope relaxed atomics: execute at the coherence point (MALL), bypass
// L1/L2 -> no cache-maintenance instructions anywhere in the hot loop.
__device__ __forceinline__ unsigned ald(unsigned* p) {
  return __hip_atomic_load(p, __ATOMIC_RELAXED, __HIP_MEMORY_SCOPE_AGENT);
}
__device__ __forceinline__ void ast(unsigned* p, unsigned v) {
  __hip_atomic_store(p, v, __ATOMIC_RELAXED, __HIP_MEMORY_SCOPE_AGENT);
}

// ---------------- init: zero h rows t=0 (u32 view) and flags ----------------
__global__ void init_kernel(unsigned* h0, unsigned* h1, unsigned* ctr) {
  int i = blockIdx.x * blockDim.x + threadIdx.x;
  if (i < 32768) { h0[i] = 0; h1[i] = 0; }
  if (i < 128) ctr[i] = 0;
}

// ---------------- fp32 -> bf16 cast (vectorized x4) ----------------
__global__ void cast_kernel(const float* __restrict__ in, u16* __restrict__ out, int n4) {
  int i = blockIdx.x * blockDim.x + threadIdx.x;
  int stride = gridDim.x * blockDim.x;
  for (; i < n4; i += stride) {
    float4 v = ((const float4*)in)[i];
    unsigned lo = f2b_rne(v.x) | (f2b_rne(v.y) << 16);
    unsigned hi = f2b_rne(v.z) | (f2b_rne(v.w) << 16);
    ((uint2*)out)[i] = make_uint2(lo, hi);
  }
}

// ---------------- big NT GEMM: C[16384][4096] bf16 = A[16384][1024] @ B[4096][1024]^T
__global__ __launch_bounds__(256) void gemm_nt(
    const u16* __restrict__ A, const u16* __restrict__ B, u16* __restrict__ C) {
  __shared__ u16 As[128 * 32];
  __shared__ u16 Bs[128 * 32];
  const int bid = blockIdx.x;
  const int m_blk = (bid >> 5) << 7;
  const int n_blk = (bid & 31) << 7;
  const int tid = threadIdx.x;
  const int wv = tid >> 6, lane = tid & 63;
  const int q = lane >> 4, n16 = lane & 15;
  const int m0w = (wv >> 1) << 6, n0w = (wv & 1) << 6;

  const floatx4 vzero = {0.f, 0.f, 0.f, 0.f};
  floatx4 acc[4][4];
#pragma unroll
  for (int mt = 0; mt < 4; ++mt)
#pragma unroll
    for (int nt = 0; nt < 4; ++nt) acc[mt][nt] = vzero;

  for (int k0 = 0; k0 < 1024; k0 += 32) {
#pragma unroll
    for (int i = 0; i < 2; ++i) {
      int s = i * 256 + tid;           // slot 0..511
      int r = s >> 2, kk = (s & 3) << 3;
      int m = m_blk + r, k = k0 + kk;
      size_t a_off = (size_t)m * 1024 + k;
      size_t b_off = (size_t)(n_blk + r) * 1024 + k;
      __builtin_amdgcn_global_load_lds(
          (const __attribute__((address_space(1))) unsigned int*)(A + a_off),
          (__attribute__((address_space(3))) unsigned int*)(As + (size_t)(i * 256 + wv * 64) * 8),
          16, 0, 0);
      __builtin_amdgcn_global_load_lds(
          (const __attribute__((address_space(1))) unsigned int*)(B + b_off),
          (__attribute__((address_space(3))) unsigned int*)(Bs + (size_t)(i * 256 + wv * 64) * 8),
          16, 0, 0);
    }
    __syncthreads();
    short8 af[4], bf[4];
#pragma unroll
    for (int mt = 0; mt < 4; ++mt)
      af[mt] = *(const short8*)(As + (m0w + mt * 16 + n16) * 32 + q * 8);
#pragma unroll
    for (int nt = 0; nt < 4; ++nt)
      bf[nt] = *(const short8*)(Bs + (n0w + nt * 16 + n16) * 32 + q * 8);
#pragma unroll
    for (int mt = 0; mt < 4; ++mt)
#pragma unroll
      for (int nt = 0; nt < 4; ++nt)
        acc[mt][nt] = __builtin_amdgcn_mfma_f32_16x16x32_bf16(af[mt], bf[nt], acc[mt][nt], 0, 0, 0);
    __syncthreads();
  }
#pragma unroll
  for (int mt = 0; mt < 4; ++mt)
#pragma unroll
    for (int nt = 0; nt < 4; ++nt)
#pragma unroll
      for (int r = 0; r < 4; ++r) {
        int m = m_blk + m0w + mt * 16 + q * 4 + r;
        int n = n_blk + n0w + nt * 16 + n16;
        C[(size_t)m * 4096 + n] = (u16)f2b_rne(acc[mt][nt][r]);
      }
}

// ---------------- fused persistent 2-layer LSTM recurrence ----------------
// 128 WGs x 256 threads. blockIdx<64 -> layer 0, else layer 1 (one step
// behind, pipelined). H buffers are u32 "bf16-pair" blocked:
//   word(b, j) at row*32768 + (j>>4)*512 + b*8 + ((j&15)>>1), pair (j, j+1).
// Protocol (fence-free):
//   - h written via agent-scope relaxed atomic u32 stores (write-through at
//     MALL; each 128B line written by exactly ONE WG; never dirty in any L2).
//   - __syncthreads() drains each wave's vmcnt -> all h stores acked at MALL.
//   - wave0 lane0 publishes flag[jb]=t+1 (atomic store, no RMW); wave0's 64
//     lanes poll all 64 flags in parallel (relaxed atomic loads + __all).
//   - readers use NORMAL cached vector loads for h: lines are first-touched
//     only after the flag gate, and dispatch-start L2/L1 invalidation handles
//     cross-launch staleness. No buffer_wbl2 / buffer_inv in the loop at all.
__global__ __launch_bounds__(256, 1) void lstm_fused(
    const u16* __restrict__ Wh0b,   // [4096][1024] bf16
    const u16* __restrict__ Wx1b,   // [4096][1024] bf16
    const u16* __restrict__ Wh1b,   // [4096][1024] bf16
    const u16* __restrict__ G,      // [16384][4096] bf16 (x@Wx0^T, no bias)
    const float* __restrict__ bias, // [2][4096]
    unsigned* H0u,                  // u32 blocked, 257 rows
    unsigned* H1u,
    float* __restrict__ outp,       // [256*64*1024] fp32 (layer-1 output)
    float* __restrict__ hf,         // [2*64*1024] fp32
    float* __restrict__ cf,         // [2*64*1024] fp32
    unsigned* ctr) {                // flag0[64], flag1[64]
  __shared__ float red[4][12][256];
  const int tid = threadIdx.x;
  const int wv = tid >> 6;
  const int lane = tid & 63;
  const int q = lane >> 4;
  const int n16 = lane & 15;
  const int layer = blockIdx.x >> 6;
  const int jb = blockIdx.x & 63;
  const int j0 = jb << 4;
  const int jg = j0 + n16;
  const int kq0 = wv << 8;
  unsigned* flag0 = ctr;
  unsigned* flag1 = ctr + 64;
  const floatx4 vzero = {0.f, 0.f, 0.f, 0.f};

  float bs[4];
#pragma unroll
  for (int g = 0; g < 4; ++g) bs[g] = bias[layer * 4096 + g * 1024 + jg];
  float cst[4] = {0.f, 0.f, 0.f, 0.f};

  if (layer == 0) {
    // ---------------- layer 0 ----------------
    short8 wf[4][8];
#pragma unroll
    for (int g = 0; g < 4; ++g)
#pragma unroll
      for (int c = 0; c < 8; ++c)
        wf[g][c] = *(const short8*)(Wh0b + (size_t)(g * 1024 + jg) * 1024 + kq0 + c * 32 + q * 8);
    // pin weight fragments in registers (defeat load-sinking into the loop)
#pragma unroll
    for (int g = 0; g < 4; ++g)
#pragma unroll
      for (int c = 0; c < 8; ++c) asm volatile("" : "+v"(wf[g][c]));

    // preload G fragment for t=0
    float gf[4][4];
#pragma unroll
    for (int g = 0; g < 4; ++g)
#pragma unroll
      for (int r = 0; r < 4; ++r)
        gf[g][r] = b2f(G[(size_t)(wv * 16 + q * 4 + r) * 4096 + g * 1024 + jg]);

    for (int t = 0; t < NSTEP; ++t) {
      const unsigned* hrow = H0u + (size_t)t * 32768;

      floatx4 acc[4][4];
#pragma unroll
      for (int m = 0; m < 4; ++m)
#pragma unroll
        for (int g = 0; g < 4; ++g) acc[m][g] = vzero;

#pragma unroll
      for (int c = 0; c < 8; ++c) {
        int k = kq0 + c * 32 + q * 8;
        const unsigned* base = hrow + (k >> 4) * 512 + ((k & 15) >> 1);
        short8 a[4];
#pragma unroll
        for (int m = 0; m < 4; ++m)
          a[m] = *(const short8*)(base + (m * 16 + n16) * 8);
#pragma unroll
        for (int m = 0; m < 4; ++m)
#pragma unroll
          for (int g = 0; g < 4; ++g)
            acc[m][g] = __builtin_amdgcn_mfma_f32_16x16x32_bf16(a[m], wf[g][c], acc[m][g], 0, 0, 0);
      }

      // cross-wave K reduction via LDS
#pragma unroll
      for (int m = 0; m < 4; ++m) {
        if (m == wv) continue;
        int slot = (m - (m > wv ? 1 : 0)) * 4;
#pragma unroll
        for (int g = 0; g < 4; ++g)
          *(floatx4*)&red[wv][slot + g][lane * 4] = acc[m][g];
      }
      __syncthreads();
      floatx4 tot[4];
#pragma unroll
      for (int g = 0; g < 4; ++g) tot[g] = acc[wv][g];
#pragma unroll
      for (int w2 = 0; w2 < 4; ++w2) {
        if (w2 == wv) continue;
        int slot = (wv - (wv > w2 ? 1 : 0)) * 4;
#pragma unroll
        for (int g = 0; g < 4; ++g)
          tot[g] += *(const floatx4*)&red[w2][slot + g][lane * 4];
      }

      unsigned* hnext = H0u + (size_t)(t + 1) * 32768 + jb * 512;
#pragma unroll
      for (int r = 0; r < 4; ++r) {
        float pi = tot[0][r] + gf[0][r] + bs[0];
        float pf = tot[1][r] + gf[1][r] + bs[1];
        float po = tot[2][r] + gf[2][r] + bs[2];
        float pc = tot[3][r] + gf[3][r] + bs[3];
        float cn = sigf(pf) * cst[r] + sigf(pi) * tanhf_fast(pc);
        float h = sigf(po) * tanhf_fast(cn);
        cst[r] = cn;
        int brow = wv * 16 + q * 4 + r;
        unsigned hv = f2b_rne(h);
        unsigned pv = (unsigned)__shfl_xor((int)hv, 1);
        if (!(n16 & 1)) ast(hnext + brow * 8 + (n16 >> 1), hv | (pv << 16));
        if (t == NSTEP - 1) {
          hf[brow * 1024 + jg] = h;
          cf[brow * 1024 + jg] = cn;
        }
      }

      // prefetch next-step G into registers before the barrier (cached loads)
      if (t + 1 < NSTEP) {
#pragma unroll
        for (int g = 0; g < 4; ++g)
#pragma unroll
          for (int r = 0; r < 4; ++r)
            gf[g][r] = b2f(G[(size_t)((t + 1) * 64 + wv * 16 + q * 4 + r) * 4096 + g * 1024 + jg]);
      }

      __syncthreads();  // drains vmcnt: all h atomic stores acked at MALL
      if (wv == 0) {
        if (lane == 0) ast(flag0 + jb, (unsigned)(t + 1));
        if (t + 1 < NSTEP) {
          unsigned tgt = (unsigned)(t + 1);
          int spins = 0;
          for (;;) {
            unsigned v = ald(flag0 + lane);
            if (__all((int)(v >= tgt))) break;
            __builtin_amdgcn_s_sleep(2);
            if (++spins > (1 << 17)) break;  // liveness guard
          }
        }
      }
      __syncthreads();
    }
  } else {
    // ---------------- layer 1: one step behind, K=2048 (Wx1 cat Wh1) --------
    short8 wfx[4][8], wfh[4][8];
#pragma unroll
    for (int g = 0; g < 4; ++g)
#pragma unroll
      for (int c = 0; c < 8; ++c) {
        wfx[g][c] = *(const short8*)(Wx1b + (size_t)(g * 1024 + jg) * 1024 + kq0 + c * 32 + q * 8);
        wfh[g][c] = *(const short8*)(Wh1b + (size_t)(g * 1024 + jg) * 1024 + kq0 + c * 32 + q * 8);
      }
#pragma unroll
    for (int g = 0; g < 4; ++g)
#pragma unroll
      for (int c = 0; c < 8; ++c) {
        asm volatile("" : "+v"(wfx[g][c]));
        asm volatile("" : "+v"(wfh[g][c]));
      }

    // initial gate: h0 row 1 must exist
    if (wv == 0) {
      int spins = 0;
      for (;;) {
        unsigned v = ald(flag0 + lane);
        if (__all((int)(v >= 1u))) break;
        __builtin_amdgcn_s_sleep(2);
        if (++spins > (1 << 17)) break;
      }
    }
    __syncthreads();

    for (int t = 0; t < NSTEP; ++t) {
      const unsigned* xrow = H0u + (size_t)(t + 1) * 32768;  // layer-0 out @ t
      const unsigned* hrow = H1u + (size_t)t * 32768;        // own state

      floatx4 acc[4][4];
#pragma unroll
      for (int m = 0; m < 4; ++m)
#pragma unroll
        for (int g = 0; g < 4; ++g) acc[m][g] = vzero;

      // x @ Wx1^T
#pragma unroll
      for (int c = 0; c < 8; ++c) {
        int k = kq0 + c * 32 + q * 8;
        const unsigned* base = xrow + (k >> 4) * 512 + ((k & 15) >> 1);
        short8 a[4];
#pragma unroll
        for (int m = 0; m < 4; ++m)
          a[m] = *(const short8*)(base + (m * 16 + n16) * 8);
#pragma unroll
        for (int m = 0; m < 4; ++m)
#pragma unroll
          for (int g = 0; g < 4; ++g)
            acc[m][g] = __builtin_amdgcn_mfma_f32_16x16x32_bf16(a[m], wfx[g][c], acc[m][g], 0, 0, 0);
      }
      // h @ Wh1^T
#pragma unroll
      for (int c = 0; c < 8; ++c) {
        int k = kq0 + c * 32 + q * 8;
        const unsigned* base = hrow + (k >> 4) * 512 + ((k & 15) >> 1);
        short8 a[4];
#pragma unroll
        for (int m = 0; m < 4; ++m)
          a[m] = *(const short8*)(base + (m * 16 + n16) * 8);
#pragma unroll
        for (int m = 0; m < 4; ++m)
#pragma unroll
          for (int g = 0; g < 4; ++g)
            acc[m][g] = __builtin_amdgcn_mfma_f32_16x16x32_bf16(a[m], wfh[g][c], acc[m][g], 0, 0, 0);
      }

      // cross-wave K reduction via LDS
#pragma unroll
      for (int m = 0; m < 4; ++m) {
        if (m == wv) continue;
        int slot = (m - (m > wv ? 1 : 0)) * 4;
#pragma unroll
        for (int g = 0; g < 4; ++g)
          *(floatx4*)&red[wv][slot + g][lane * 4] = acc[m][g];
      }
      __syncthreads();
      floatx4 tot[4];
#pragma unroll
      for (int g = 0; g < 4; ++g) tot[g] = acc[wv][g];
#pragma unroll
      for (int w2 = 0; w2 < 4; ++w2) {
        if (w2 == wv) continue;
        int slot = (wv - (wv > w2 ? 1 : 0)) * 4;
#pragma unroll
        for (int g = 0; g < 4; ++g)
          tot[g] += *(const floatx4*)&red[w2][slot + g][lane * 4];
      }

      unsigned* hnext = H1u + (size_t)(t + 1) * 32768 + jb * 512;
#pragma unroll
      for (int r = 0; r < 4; ++r) {
        float pi = tot[0][r] + bs[0];
        float pf = tot[1][r] + bs[1];
        float po = tot[2][r] + bs[2];
        float pc = tot[3][r] + bs[3];
        float cn = sigf(pf) * cst[r] + sigf(pi) * tanhf_fast(pc);
        float h = sigf(po) * tanhf_fast(cn);
        cst[r] = cn;
        int brow = wv * 16 + q * 4 + r;
        unsigned hv = f2b_rne(h);
        unsigned pv = (unsigned)__shfl_xor((int)hv, 1);
        if (!(n16 & 1)) ast(hnext + brow * 8 + (n16 >> 1), hv | (pv << 16));
        outp[((size_t)t * 64 + brow) * 1024 + jg] = h;
        if (t == NSTEP - 1) {
          hf[65536 + brow * 1024 + jg] = h;
          cf[65536 + brow * 1024 + jg] = cn;
        }
      }

      __syncthreads();  // drains vmcnt: h stores acked at MALL
      if (wv == 0) {
        if (lane == 0) ast(flag1 + jb, (unsigned)(t + 1));
        if (t + 1 < NSTEP) {
          unsigned tgt = (unsigned)(t + 1);
          int spins = 0;
          for (;;) {
            unsigned v1 = ald(flag1 + lane);
            unsigned v0 = ald(flag0 + lane);
            if (__all((int)((v1 >= tgt) & (v0 >= tgt + 1)))) break;
            __builtin_amdgcn_s_sleep(2);
            if (++spins > (1 << 17)) break;
          }
        }
      }
      __syncthreads();
    }
  }
}

// ---------------- launch ----------------
extern "C" void kernel_launch(void* const* d_in, const int* in_sizes, int n_in,
                              void* d_out, int out_size, void* d_ws, size_t ws_size,
                              hipStream_t stream) {
  const float* X  = (const float*)d_in[0];   // [256][64][1024]
  const float* Wx = (const float*)d_in[1];   // [2][4096][1024]
  const float* Wh = (const float*)d_in[2];   // [2][4096][1024]
  const float* b  = (const float*)d_in[3];   // [2][4096]
  float* out = (float*)d_out;

  char* ws = (char*)d_ws;
  u16* Xbf  = (u16*)(ws);                         // 33,554,432 B
  u16* Wxbf = (u16*)(ws + 33554432);              // 16,777,216 B
  u16* Whbf = (u16*)(ws + 50331648);              // 16,777,216 B
  unsigned* H0 = (unsigned*)(ws + 67108864);      // 33,685,504 B (257*131072)
  unsigned* H1 = (unsigned*)(ws + 100794368);     // 33,685,504 B
  u16* G    = (u16*)(ws + 134479872);             // 134,217,728 B
  unsigned* ctr = (unsigned*)(ws + 268697600);    // 512 B

  float* out_seq = out;                // 16,777,216 floats
  float* Hf = out + 16777216;          // 131,072 floats
  float* Cf = out + 16777216 + 131072; // 131,072 floats

  init_kernel<<<256, 256, 0, stream>>>(H0, H1, ctr);
  cast_kernel<<<2048, 256, 0, stream>>>(X, Xbf, 16777216 / 4);
  cast_kernel<<<2048, 256, 0, stream>>>(Wx, Wxbf, 8388608 / 4);
  cast_kernel<<<2048, 256, 0, stream>>>(Wh, Whbf, 8388608 / 4);

  // layer-0 input GEMM: G = X @ Wx0^T (layer-1's input GEMM is fused in-loop)
  gemm_nt<<<4096, 256, 0, stream>>>(Xbf, Wxbf, G);

  // fused pipelined 2-layer recurrence (fence-free flag barrier)
  lstm_fused<<<128, 256, 0, stream>>>(Whbf, Wxbf + 4194304, Whbf + 4194304, G, b,
                                      H0, H1, out_seq, Hf, Cf, ctr);
}

// Round 3
// 5549.811 us; speedup vs baseline: 1.3732x; 1.0638x over previous
//
#include <hip/hip_runtime.h>
#include <cstdint>
#include <cstddef>

typedef __attribute__((ext_vector_type(8))) short short8;
typedef __attribute__((ext_vector_type(4))) float floatx4;
typedef unsigned short u16;

#define NSTEP 256

__device__ __forceinline__ unsigned f2b_rne(float x) {
  unsigned u = __builtin_bit_cast(unsigned, x);
  return (u + 0x7fffu + ((u >> 16) & 1u)) >> 16;
}
__device__ __forceinline__ float b2f(u16 b) {
  unsigned u = ((unsigned)b) << 16;
  return __builtin_bit_cast(float, u);
}
__device__ __forceinline__ float sigf(float x) {
  x = fminf(fmaxf(x, -30.f), 30.f);
  return __builtin_amdgcn_rcpf(1.f + __expf(-x));
}
__device__ __forceinline__ float tanhf_fast(float x) {
  x = fminf(fmaxf(x, -15.f), 15.f);
  float e = __expf(2.f * x);
  return (e - 1.f) * __builtin_amdgcn_rcpf(e + 1.f);
}

// agent-scope relaxed atomics: execute at the coherence point (MALL), bypass
// L1/L2 -> no cache-maintenance instructions anywhere in the hot loop.
__device__ __forceinline__ unsigned ald(unsigned* p) {
  return __hip_atomic_load(p, __ATOMIC_RELAXED, __HIP_MEMORY_SCOPE_AGENT);
}
__device__ __forceinline__ void ast(unsigned* p, unsigned v) {
  __hip_atomic_store(p, v, __ATOMIC_RELAXED, __HIP_MEMORY_SCOPE_AGENT);
}

// ---------------- init: zero h rows t=0 (u32 view) and counters ----------------
__global__ void init_kernel(unsigned* h0, unsigned* h1, unsigned* ctr) {
  int i = blockIdx.x * blockDim.x + threadIdx.x;
  if (i < 32768) { h0[i] = 0; h1[i] = 0; }
  if (i < 128) ctr[i] = 0;
}

// ---------------- fp32 -> bf16 cast (vectorized x4) ----------------
__global__ void cast_kernel(const float* __restrict__ in, u16* __restrict__ out, int n4) {
  int i = blockIdx.x * blockDim.x + threadIdx.x;
  int stride = gridDim.x * blockDim.x;
  for (; i < n4; i += stride) {
    float4 v = ((const float4*)in)[i];
    unsigned lo = f2b_rne(v.x) | (f2b_rne(v.y) << 16);
    unsigned hi = f2b_rne(v.z) | (f2b_rne(v.w) << 16);
    ((uint2*)out)[i] = make_uint2(lo, hi);
  }
}

// ---------------- big NT GEMM: C[16384][4096] bf16 = A[16384][1024] @ B[4096][1024]^T
__global__ __launch_bounds__(256) void gemm_nt(
    const u16* __restrict__ A, const u16* __restrict__ B, u16* __restrict__ C) {
  __shared__ u16 As[128 * 32];
  __shared__ u16 Bs[128 * 32];
  const int bid = blockIdx.x;
  const int m_blk = (bid >> 5) << 7;
  const int n_blk = (bid & 31) << 7;
  const int tid = threadIdx.x;
  const int wv = tid >> 6, lane = tid & 63;
  const int q = lane >> 4, n16 = lane & 15;
  const int m0w = (wv >> 1) << 6, n0w = (wv & 1) << 6;

  const floatx4 vzero = {0.f, 0.f, 0.f, 0.f};
  floatx4 acc[4][4];
#pragma unroll
  for (int mt = 0; mt < 4; ++mt)
#pragma unroll
    for (int nt = 0; nt < 4; ++nt) acc[mt][nt] = vzero;

  for (int k0 = 0; k0 < 1024; k0 += 32) {
#pragma unroll
    for (int i = 0; i < 2; ++i) {
      int s = i * 256 + tid;           // slot 0..511
      int r = s >> 2, kk = (s & 3) << 3;
      int m = m_blk + r, k = k0 + kk;
      size_t a_off = (size_t)m * 1024 + k;
      size_t b_off = (size_t)(n_blk + r) * 1024 + k;
      __builtin_amdgcn_global_load_lds(
          (const __attribute__((address_space(1))) unsigned int*)(A + a_off),
          (__attribute__((address_space(3))) unsigned int*)(As + (size_t)(i * 256 + wv * 64) * 8),
          16, 0, 0);
      __builtin_amdgcn_global_load_lds(
          (const __attribute__((address_space(1))) unsigned int*)(B + b_off),
          (__attribute__((address_space(3))) unsigned int*)(Bs + (size_t)(i * 256 + wv * 64) * 8),
          16, 0, 0);
    }
    __syncthreads();
    short8 af[4], bf[4];
#pragma unroll
    for (int mt = 0; mt < 4; ++mt)
      af[mt] = *(const short8*)(As + (m0w + mt * 16 + n16) * 32 + q * 8);
#pragma unroll
    for (int nt = 0; nt < 4; ++nt)
      bf[nt] = *(const short8*)(Bs + (n0w + nt * 16 + n16) * 32 + q * 8);
#pragma unroll
    for (int mt = 0; mt < 4; ++mt)
#pragma unroll
      for (int nt = 0; nt < 4; ++nt)
        acc[mt][nt] = __builtin_amdgcn_mfma_f32_16x16x32_bf16(af[mt], bf[nt], acc[mt][nt], 0, 0, 0);
    __syncthreads();
  }
#pragma unroll
  for (int mt = 0; mt < 4; ++mt)
#pragma unroll
    for (int nt = 0; nt < 4; ++nt)
#pragma unroll
      for (int r = 0; r < 4; ++r) {
        int m = m_blk + m0w + mt * 16 + q * 4 + r;
        int n = n_blk + n0w + nt * 16 + n16;
        C[(size_t)m * 4096 + n] = (u16)f2b_rne(acc[mt][nt][r]);
      }
}

// ---------------- fused persistent 2-layer LSTM recurrence ----------------
// 128 WGs x 256 threads. blockIdx<64 -> layer 0, else layer 1 (one step
// behind, pipelined). H buffers are u32 "bf16-pair" blocked:
//   word(b, j) at row*32768 + (j>>4)*512 + b*8 + ((j&15)>>1), pair (j, j+1).
// Sync protocol (round 3): fence-free + MINIMAL MALL traffic.
//   - h written via agent-scope relaxed atomic u32 stores (write-through at
//     MALL; each line written by exactly ONE WG; never dirty in any L2).
//   - __syncthreads() drains each wave's vmcnt -> h stores acked at MALL.
//   - tid0 does ONE relaxed fetch_add on a per-layer counter (own 128B line);
//     tid0 polls the single counter dword (1 lane, 1 dword per WG — round 2's
//     64-lane x 128-WG flag polling hammered 2 shared lines at MALL and is
//     the suspected 20us/step serializer).
//   - G-prefetch / outp / final stores are issued BETWEEN publish and poll so
//     their HBM latency overlaps the wait instead of sitting on the critical
//     chain (round 2 drained them BEFORE the publish barrier).
//   - readers use NORMAL cached loads for h: lines are first-touched only
//     after the counter gate; dispatch-start invalidation covers staleness.
__global__ __launch_bounds__(256, 1) void lstm_fused(
    const u16* __restrict__ Wh0b,   // [4096][1024] bf16
    const u16* __restrict__ Wx1b,   // [4096][1024] bf16
    const u16* __restrict__ Wh1b,   // [4096][1024] bf16
    const u16* __restrict__ G,      // [16384][4096] bf16 (x@Wx0^T, no bias)
    const float* __restrict__ bias, // [2][4096]
    unsigned* H0u,                  // u32 blocked, 257 rows
    unsigned* H1u,
    float* __restrict__ outp,       // [256*64*1024] fp32 (layer-1 output)
    float* __restrict__ hf,         // [2*64*1024] fp32
    float* __restrict__ cf,         // [2*64*1024] fp32
    unsigned* ctr) {                // ctr0 @ [0], ctr1 @ [32] (separate lines)
  __shared__ float red[4][12][256];
  const int tid = threadIdx.x;
  const int wv = tid >> 6;
  const int lane = tid & 63;
  const int q = lane >> 4;
  const int n16 = lane & 15;
  const int layer = blockIdx.x >> 6;
  const int jb = blockIdx.x & 63;
  const int j0 = jb << 4;
  const int jg = j0 + n16;
  const int kq0 = wv << 8;
  unsigned* ctr0 = ctr;
  unsigned* ctr1 = ctr + 32;
  const floatx4 vzero = {0.f, 0.f, 0.f, 0.f};

  float bs[4];
#pragma unroll
  for (int g = 0; g < 4; ++g) bs[g] = bias[layer * 4096 + g * 1024 + jg];
  float cst[4] = {0.f, 0.f, 0.f, 0.f};

  if (layer == 0) {
    // ---------------- layer 0 ----------------
    short8 wf[4][8];
#pragma unroll
    for (int g = 0; g < 4; ++g)
#pragma unroll
      for (int c = 0; c < 8; ++c)
        wf[g][c] = *(const short8*)(Wh0b + (size_t)(g * 1024 + jg) * 1024 + kq0 + c * 32 + q * 8);
    // pin weight fragments (defeat rematerialization into the loop)
#pragma unroll
    for (int g = 0; g < 4; ++g)
#pragma unroll
      for (int c = 0; c < 8; ++c) asm volatile("" : "+v"(wf[g][c]));

    // preload G fragment for t=0
    float gf[4][4];
#pragma unroll
    for (int g = 0; g < 4; ++g)
#pragma unroll
      for (int r = 0; r < 4; ++r)
        gf[g][r] = b2f(G[(size_t)(wv * 16 + q * 4 + r) * 4096 + g * 1024 + jg]);

    for (int t = 0; t < NSTEP; ++t) {
      const unsigned* hrow = H0u + (size_t)t * 32768;

      floatx4 acc[4][4];
#pragma unroll
      for (int m = 0; m < 4; ++m)
#pragma unroll
        for (int g = 0; g < 4; ++g) acc[m][g] = vzero;

#pragma unroll
      for (int c = 0; c < 8; ++c) {
        int k = kq0 + c * 32 + q * 8;
        const unsigned* base = hrow + (k >> 4) * 512 + ((k & 15) >> 1);
        short8 a[4];
#pragma unroll
        for (int m = 0; m < 4; ++m)
          a[m] = *(const short8*)(base + (m * 16 + n16) * 8);
#pragma unroll
        for (int m = 0; m < 4; ++m)
#pragma unroll
          for (int g = 0; g < 4; ++g)
            acc[m][g] = __builtin_amdgcn_mfma_f32_16x16x32_bf16(a[m], wf[g][c], acc[m][g], 0, 0, 0);
      }

      // cross-wave K reduction via LDS
#pragma unroll
      for (int m = 0; m < 4; ++m) {
        if (m == wv) continue;
        int slot = (m - (m > wv ? 1 : 0)) * 4;
#pragma unroll
        for (int g = 0; g < 4; ++g)
          *(floatx4*)&red[wv][slot + g][lane * 4] = acc[m][g];
      }
      __syncthreads();
      floatx4 tot[4];
#pragma unroll
      for (int g = 0; g < 4; ++g) tot[g] = acc[wv][g];
#pragma unroll
      for (int w2 = 0; w2 < 4; ++w2) {
        if (w2 == wv) continue;
        int slot = (wv - (wv > w2 ? 1 : 0)) * 4;
#pragma unroll
        for (int g = 0; g < 4; ++g)
          tot[g] += *(const floatx4*)&red[w2][slot + g][lane * 4];
      }

      unsigned* hnext = H0u + (size_t)(t + 1) * 32768 + jb * 512;
      float hsv[4];
#pragma unroll
      for (int r = 0; r < 4; ++r) {
        float pi = tot[0][r] + gf[0][r] + bs[0];
        float pf = tot[1][r] + gf[1][r] + bs[1];
        float po = tot[2][r] + gf[2][r] + bs[2];
        float pc = tot[3][r] + gf[3][r] + bs[3];
        float cn = sigf(pf) * cst[r] + sigf(pi) * tanhf_fast(pc);
        float h = sigf(po) * tanhf_fast(cn);
        cst[r] = cn;
        hsv[r] = h;
        int brow = wv * 16 + q * 4 + r;
        unsigned hv = f2b_rne(h);
        unsigned pv = (unsigned)__shfl_xor((int)hv, 1);
        if (!(n16 & 1)) ast(hnext + brow * 8 + (n16 >> 1), hv | (pv << 16));
      }

      __syncthreads();  // drains vmcnt: all h atomic stores acked at MALL
      // publish FIRST (critical path), then off-critical-path work
      if (tid == 0)
        __hip_atomic_fetch_add(ctr0, 1u, __ATOMIC_RELAXED, __HIP_MEMORY_SCOPE_AGENT);
      // G prefetch for t+1 (HBM latency overlaps the poll wait below)
      if (t + 1 < NSTEP) {
#pragma unroll
        for (int g = 0; g < 4; ++g)
#pragma unroll
          for (int r = 0; r < 4; ++r)
            gf[g][r] = b2f(G[(size_t)((t + 1) * 64 + wv * 16 + q * 4 + r) * 4096 + g * 1024 + jg]);
      }
      if (t == NSTEP - 1) {
#pragma unroll
        for (int r = 0; r < 4; ++r) {
          int brow = wv * 16 + q * 4 + r;
          hf[brow * 1024 + jg] = hsv[r];
          cf[brow * 1024 + jg] = cst[r];
        }
      }
      if (tid == 0 && t + 1 < NSTEP) {
        unsigned tgt = 64u * (unsigned)(t + 1);
        int spins = 0;
        while (ald(ctr0) < tgt) {
          __builtin_amdgcn_s_sleep(2);
          if (++spins > (1 << 17)) break;  // liveness guard
        }
      }
      __syncthreads();
    }
  } else {
    // ---------------- layer 1: one step behind, K=2048 (Wx1 cat Wh1) --------
    short8 wfx[4][8], wfh[4][8];
#pragma unroll
    for (int g = 0; g < 4; ++g)
#pragma unroll
      for (int c = 0; c < 8; ++c) {
        wfx[g][c] = *(const short8*)(Wx1b + (size_t)(g * 1024 + jg) * 1024 + kq0 + c * 32 + q * 8);
        wfh[g][c] = *(const short8*)(Wh1b + (size_t)(g * 1024 + jg) * 1024 + kq0 + c * 32 + q * 8);
      }
#pragma unroll
    for (int g = 0; g < 4; ++g)
#pragma unroll
      for (int c = 0; c < 8; ++c) {
        asm volatile("" : "+v"(wfx[g][c]));
        asm volatile("" : "+v"(wfh[g][c]));
      }

    // initial gate: h0 row 1 must exist
    if (tid == 0) {
      int spins = 0;
      while (ald(ctr0) < 64u) {
        __builtin_amdgcn_s_sleep(2);
        if (++spins > (1 << 17)) break;
      }
    }
    __syncthreads();

    for (int t = 0; t < NSTEP; ++t) {
      const unsigned* xrow = H0u + (size_t)(t + 1) * 32768;  // layer-0 out @ t
      const unsigned* hrow = H1u + (size_t)t * 32768;        // own state

      floatx4 acc[4][4];
#pragma unroll
      for (int m = 0; m < 4; ++m)
#pragma unroll
        for (int g = 0; g < 4; ++g) acc[m][g] = vzero;

      // x @ Wx1^T
#pragma unroll
      for (int c = 0; c < 8; ++c) {
        int k = kq0 + c * 32 + q * 8;
        const unsigned* base = xrow + (k >> 4) * 512 + ((k & 15) >> 1);
        short8 a[4];
#pragma unroll
        for (int m = 0; m < 4; ++m)
          a[m] = *(const short8*)(base + (m * 16 + n16) * 8);
#pragma unroll
        for (int m = 0; m < 4; ++m)
#pragma unroll
          for (int g = 0; g < 4; ++g)
            acc[m][g] = __builtin_amdgcn_mfma_f32_16x16x32_bf16(a[m], wfx[g][c], acc[m][g], 0, 0, 0);
      }
      // h @ Wh1^T
#pragma unroll
      for (int c = 0; c < 8; ++c) {
        int k = kq0 + c * 32 + q * 8;
        const unsigned* base = hrow + (k >> 4) * 512 + ((k & 15) >> 1);
        short8 a[4];
#pragma unroll
        for (int m = 0; m < 4; ++m)
          a[m] = *(const short8*)(base + (m * 16 + n16) * 8);
#pragma unroll
        for (int m = 0; m < 4; ++m)
#pragma unroll
          for (int g = 0; g < 4; ++g)
            acc[m][g] = __builtin_amdgcn_mfma_f32_16x16x32_bf16(a[m], wfh[g][c], acc[m][g], 0, 0, 0);
      }

      // cross-wave K reduction via LDS
#pragma unroll
      for (int m = 0; m < 4; ++m) {
        if (m == wv) continue;
        int slot = (m - (m > wv ? 1 : 0)) * 4;
#pragma unroll
        for (int g = 0; g < 4; ++g)
          *(floatx4*)&red[wv][slot + g][lane * 4] = acc[m][g];
      }
      __syncthreads();
      floatx4 tot[4];
#pragma unroll
      for (int g = 0; g < 4; ++g) tot[g] = acc[wv][g];
#pragma unroll
      for (int w2 = 0; w2 < 4; ++w2) {
        if (w2 == wv) continue;
        int slot = (wv - (wv > w2 ? 1 : 0)) * 4;
#pragma unroll
        for (int g = 0; g < 4; ++g)
          tot[g] += *(const floatx4*)&red[w2][slot + g][lane * 4];
      }

      unsigned* hnext = H1u + (size_t)(t + 1) * 32768 + jb * 512;
      float hsv[4];
#pragma unroll
      for (int r = 0; r < 4; ++r) {
        float pi = tot[0][r] + bs[0];
        float pf = tot[1][r] + bs[1];
        float po = tot[2][r] + bs[2];
        float pc = tot[3][r] + bs[3];
        float cn = sigf(pf) * cst[r] + sigf(pi) * tanhf_fast(pc);
        float h = sigf(po) * tanhf_fast(cn);
        cst[r] = cn;
        hsv[r] = h;
        int brow = wv * 16 + q * 4 + r;
        unsigned hv = f2b_rne(h);
        unsigned pv = (unsigned)__shfl_xor((int)hv, 1);
        if (!(n16 & 1)) ast(hnext + brow * 8 + (n16 >> 1), hv | (pv << 16));
      }

      __syncthreads();  // drains vmcnt: h stores acked at MALL
      // publish FIRST, then off-critical-path output stores
      if (tid == 0)
        __hip_atomic_fetch_add(ctr1, 1u, __ATOMIC_RELAXED, __HIP_MEMORY_SCOPE_AGENT);
#pragma unroll
      for (int r = 0; r < 4; ++r) {
        int brow = wv * 16 + q * 4 + r;
        outp[((size_t)t * 64 + brow) * 1024 + jg] = hsv[r];
      }
      if (t == NSTEP - 1) {
#pragma unroll
        for (int r = 0; r < 4; ++r) {
          int brow = wv * 16 + q * 4 + r;
          hf[65536 + brow * 1024 + jg] = hsv[r];
          cf[65536 + brow * 1024 + jg] = cst[r];
        }
      }
      if (tid == 0 && t + 1 < NSTEP) {
        unsigned tgt1 = 64u * (unsigned)(t + 1);
        unsigned tgt0 = 64u * (unsigned)(t + 2);
        int spins = 0;
        while (ald(ctr1) < tgt1 || ald(ctr0) < tgt0) {
          __builtin_amdgcn_s_sleep(2);
          if (++spins > (1 << 17)) break;  // liveness guard
        }
      }
      __syncthreads();
    }
  }
}

// ---------------- launch ----------------
extern "C" void kernel_launch(void* const* d_in, const int* in_sizes, int n_in,
                              void* d_out, int out_size, void* d_ws, size_t ws_size,
                              hipStream_t stream) {
  const float* X  = (const float*)d_in[0];   // [256][64][1024]
  const float* Wx = (const float*)d_in[1];   // [2][4096][1024]
  const float* Wh = (const float*)d_in[2];   // [2][4096][1024]
  const float* b  = (const float*)d_in[3];   // [2][4096]
  float* out = (float*)d_out;

  char* ws = (char*)d_ws;
  u16* Xbf  = (u16*)(ws);                         // 33,554,432 B
  u16* Wxbf = (u16*)(ws + 33554432);              // 16,777,216 B
  u16* Whbf = (u16*)(ws + 50331648);              // 16,777,216 B
  unsigned* H0 = (unsigned*)(ws + 67108864);      // 33,685,504 B (257*131072)
  unsigned* H1 = (unsigned*)(ws + 100794368);     // 33,685,504 B
  u16* G    = (u16*)(ws + 134479872);             // 134,217,728 B
  unsigned* ctr = (unsigned*)(ws + 268697600);    // 512 B

  float* out_seq = out;                // 16,777,216 floats
  float* Hf = out + 16777216;          // 131,072 floats
  float* Cf = out + 16777216 + 131072; // 131,072 floats

  init_kernel<<<256, 256, 0, stream>>>(H0, H1, ctr);
  cast_kernel<<<2048, 256, 0, stream>>>(X, Xbf, 16777216 / 4);
  cast_kernel<<<2048, 256, 0, stream>>>(Wx, Wxbf, 8388608 / 4);
  cast_kernel<<<2048, 256, 0, stream>>>(Wh, Whbf, 8388608 / 4);

  // layer-0 input GEMM: G = X @ Wx0^T (layer-1's input GEMM is fused in-loop)
  gemm_nt<<<4096, 256, 0, stream>>>(Xbf, Wxbf, G);

  // fused pipelined 2-layer recurrence (fence-free, single-counter barrier)
  lstm_fused<<<128, 256, 0, stream>>>(Whbf, Wxbf + 4194304, Whbf + 4194304, G, b,
                                      H0, H1, out_seq, Hf, Cf, ctr);
}